// Round 14
// baseline (276.175 us; speedup 1.0000x reference)
//
#include <hip/hip_runtime.h>
#include <math.h>

typedef __attribute__((ext_vector_type(4))) float f4;
typedef __attribute__((ext_vector_type(8))) short s8v;   // bf16x8 MFMA fragment
typedef __attribute__((ext_vector_type(4))) unsigned int u4v;
typedef __attribute__((ext_vector_type(2))) unsigned int u2v;

#define NVOX 262144        // 64^3
#define MB_TOT 67108864    // 4*64*NVOX

__device__ __forceinline__ float sigm(float x){ return 1.0f/(1.0f+expf(-x)); }
__device__ __forceinline__ unsigned short f2b(float f){
  unsigned x = __float_as_uint(f);
  return (unsigned short)((x + 0x7fffu + ((x>>16)&1u)) >> 16);
}
__device__ __forceinline__ unsigned cvtpk(float lo, float hi){
  unsigned r;
  asm("v_cvt_pk_bf16_f32 %0, %1, %2" : "=v"(r) : "v"(lo), "v"(hi));
  return r;
}
__device__ __forceinline__ float bl(unsigned u){ return __uint_as_float(u<<16); }
__device__ __forceinline__ float bh(unsigned u){ return __uint_as_float(u & 0xffff0000u); }

// ---------------- pass 1: zero-shuffle register accumulation ----------------
// 512 blocks x 1024 threads; block = (mc = b>>1, half = b&1 -> i in [half*32, half*32+32)).
// thread: chunk = tid&15 (z-quad), j = tid>>4. i is (half, literal) -> i-hat weights fold.
// Per row: ~14 VALU, ZERO shfl/LDS (r13's 18 shfl/row x 32 rows = ~18K DS-pipe ops/CU was
// the post-latency bottleneck). 8 named wz accumulators A[px][{lzc,lzc+1}], 2 bs accs.
// Merge: 16+2 LDS atomics/thread into 4 banked copies (4x less serialization), then
// 64 global atomicAdds onto memset'd workspace.

#define LDI(I) (*reinterpret_cast<const f4*>(xp + (size_t)((I)*64 + j)*64 + chunk*4))

#define BODY(I, V) { \
  float s_ = ((V).x+(V).y)+((V).z+(V).w); \
  float wB_ = (V).x*wq0 + (V).y*wq1 + (V).z*wq2 + (V).w*wq3; \
  float wA_ = s_ - wB_; \
  if ((((I)>>4)&1)==0) blo += s_; else bhi += s_; \
  const int   li_  = ((I)<8)?0:(((I)>=56)?3:(((I)-8)>>4)); \
  const float wi_  = ((I)<8||(I)>=56)?0.0f:(((I)+0.5f)*0.0625f-0.5f-(float)li_); \
  const float h0_ = (li_==0)?(1.0f-wi_):0.0f; \
  const float h1_ = (li_==1)?(1.0f-wi_):((li_==0)?wi_:0.0f); \
  const float h2_ = (li_==2)?(1.0f-wi_):((li_==1)?wi_:0.0f); \
  const float h3_ = (li_==3)?(1.0f-wi_):((li_==2)?wi_:0.0f); \
  if (h0_ != 0.0f){ aL0 += h0_*wA_; aH0 += h0_*wB_; } \
  if (h1_ != 0.0f){ aL1 += h1_*wA_; aH1 += h1_*wB_; } \
  if (h2_ != 0.0f){ aL2 += h2_*wA_; aH2 += h2_*wB_; } \
  if (h3_ != 0.0f){ aL3 += h3_*wA_; aH3 += h3_*wB_; } \
}

#define B4(IB) { \
  f4 v0_ = LDI((IB)+0); \
  f4 v1_ = LDI((IB)+1); \
  f4 v2_ = LDI((IB)+2); \
  f4 v3_ = LDI((IB)+3); \
  BODY((IB)+0, v0_); \
  BODY((IB)+1, v1_); \
  BODY((IB)+2, v2_); \
  BODY((IB)+3, v3_); \
}

#define HALF32(I0) B4(I0) B4((I0)+4) B4((I0)+8) B4((I0)+12) B4((I0)+16) B4((I0)+20) B4((I0)+24) B4((I0)+28)

__global__ __launch_bounds__(1024) void k_pass1(const float* __restrict__ x,
                                                float* __restrict__ dsums,
                                                float* __restrict__ xbsums){
  __shared__ float xbL[4][64];
  __shared__ float bsL[4][64];
  int tid = threadIdx.x;
  int b = blockIdx.x;
  int mc   = b >> 1;
  int half = b & 1;
  if (tid < 256){ xbL[tid>>6][tid&63]=0.f; bsL[tid>>6][tid&63]=0.f; }
  const float* xp = x + (size_t)mc * NVOX;
  int chunk = tid & 15;
  int j     = tid >> 4;
  // z-weights (lzc uniform within a chunk; chunk*4 quad-aligned to the knots)
  float wq0,wq1,wq2,wq3; int lzc;
  {
    int z0 = chunk*4;
    lzc = (z0<8)?0:((z0>=56)?3:((z0-8)>>4));
    wq0 = (z0  <8||z0  >=56)?0.0f:((z0+0.5f)*0.0625f-0.5f-(float)lzc);
    wq1 = (z0+1<8||z0+1>=56)?0.0f:((z0+1.5f)*0.0625f-0.5f-(float)lzc);
    wq2 = (z0+2<8||z0+2>=56)?0.0f:((z0+2.5f)*0.0625f-0.5f-(float)lzc);
    wq3 = (z0+3<8||z0+3>=56)?0.0f:((z0+3.5f)*0.0625f-0.5f-(float)lzc);
  }
  float cjA, cjB; int lj;
  {
    float cj = fminf(fmaxf((j+0.5f)*0.0625f-0.5f, 0.0f), 3.0f);
    lj = (int)cj; float wj = cj - (float)lj;
    cjA = 1.0f - wj; cjB = wj;
  }
  int jq = j >> 4, kq = chunk >> 2;

  float aL0=0.f,aL1=0.f,aL2=0.f,aL3=0.f;
  float aH0=0.f,aH1=0.f,aH2=0.f,aH3=0.f;
  float blo=0.f, bhi=0.f;

  if (half == 0){ HALF32(0) } else { HALF32(32) }

  __syncthreads();
  int cp = (tid >> 8) & 3;     // 4 banked copies to cut atomic serialization
  {
    // xb merge: 16 cells (guards keep indices valid; skipped terms are exact zeros)
    int p00 = lj*4 + lzc;
    atomicAdd(&xbL[cp][ 0 + p00], cjA*aL0);
    atomicAdd(&xbL[cp][16 + p00], cjA*aL1);
    atomicAdd(&xbL[cp][32 + p00], cjA*aL2);
    atomicAdd(&xbL[cp][48 + p00], cjA*aL3);
    if (lzc < 3){
      atomicAdd(&xbL[cp][ 0 + p00+1], cjA*aH0);
      atomicAdd(&xbL[cp][16 + p00+1], cjA*aH1);
      atomicAdd(&xbL[cp][32 + p00+1], cjA*aH2);
      atomicAdd(&xbL[cp][48 + p00+1], cjA*aH3);
    }
    if (lj < 3){
      atomicAdd(&xbL[cp][ 0 + p00+4], cjB*aL0);
      atomicAdd(&xbL[cp][16 + p00+4], cjB*aL1);
      atomicAdd(&xbL[cp][32 + p00+4], cjB*aL2);
      atomicAdd(&xbL[cp][48 + p00+4], cjB*aL3);
      if (lzc < 3){
        atomicAdd(&xbL[cp][ 0 + p00+5], cjB*aH0);
        atomicAdd(&xbL[cp][16 + p00+5], cjB*aH1);
        atomicAdd(&xbL[cp][32 + p00+5], cjB*aH2);
        atomicAdd(&xbL[cp][48 + p00+5], cjB*aH3);
      }
    }
    atomicAdd(&bsL[cp][(half*2  )*16 + jq*4 + kq], blo);
    atomicAdd(&bsL[cp][(half*2+1)*16 + jq*4 + kq], bhi);
  }
  __syncthreads();
  if (tid < 64){
    float xs = xbL[0][tid]+xbL[1][tid]+xbL[2][tid]+xbL[3][tid];
    float bs = bsL[0][tid]+bsL[1][tid]+bsL[2][tid]+bsL[3][tid];
    atomicAdd(&xbsums[(size_t)mc*64 + tid], xs);
    atomicAdd(&dsums [(size_t)mc*64 + tid], bs);
  }
}

// ---------------- pass 2: all tiny MLPs (single block) + wf->bf16 conversion ----------------
__global__ __launch_bounds__(256) void k_pass2(
    const float* __restrict__ dsums, const float* __restrict__ xbsums,
    const float* __restrict__ wq1, const float* __restrict__ bq1,
    const float* __restrict__ wq2, const float* __restrict__ bq2,
    const float* __restrict__ wa1, const float* __restrict__ ba1,
    const float* __restrict__ wa2, const float* __restrict__ ba2,
    const float* __restrict__ wf,  const float* __restrict__ bfv,
    const float* __restrict__ wg1, const float* __restrict__ bg1,
    const float* __restrict__ wg2, const float* __restrict__ bg2,
    float* __restrict__ wsa, float* __restrict__ wsgate,
    float* __restrict__ wsqw, float* __restrict__ wsinv,
    unsigned short* __restrict__ wfb,
    float* __restrict__ outp)
{
  __shared__ float sGap[256];
  __shared__ float sA[256];
  __shared__ float sCm[256];
  __shared__ float sG[256];
  __shared__ float sGG[16];
  __shared__ float sQw[4];
  int tid = threadIdx.x;
  int m = tid>>6, c = tid&63;
  for (int t = tid; t < 4096; t += 256) wfb[t] = f2b(wf[t]);
  {
    float s=0.f;
    const float* dp = dsums + (size_t)tid*64;
    for (int p=0;p<64;++p) s += dp[p];
    sGap[tid] = s * (1.0f/262144.0f);
  }
  {
    int p = c;
    float h0=0,h1=0,h2=0,h3=0;
    for (int cc=0; cc<64; ++cc){
      float dm = dsums[((size_t)(m*64+cc))*64+p] * (1.0f/4096.0f);
      h0 += dm * wa1[0*64+cc];
      h1 += dm * wa1[1*64+cc];
      h2 += dm * wa1[2*64+cc];
      h3 += dm * wa1[3*64+cc];
    }
    h0 = fmaxf(h0 + ba1[0], 0.f);
    h1 = fmaxf(h1 + ba1[1], 0.f);
    h2 = fmaxf(h2 + ba1[2], 0.f);
    h3 = fmaxf(h3 + ba1[3], 0.f);
    float s = h0*wa2[0] + h1*wa2[1] + h2*wa2[2] + h3*wa2[3] + ba2[0];
    float aa = sigm(s);
    sA[tid] = aa;
    wsa[tid] = aa;
  }
  __syncthreads();
  if (tid < 4){
    int mm = tid;
    float q0=0,q1=0,q2=0,q3=0;
    for (int cc=0; cc<64; ++cc){
      float g = sGap[mm*64+cc];
      q0 += g*wq1[0*64+cc];
      q1 += g*wq1[1*64+cc];
      q2 += g*wq1[2*64+cc];
      q3 += g*wq1[3*64+cc];
    }
    q0 = fmaxf(q0+bq1[0],0.f); q1 = fmaxf(q1+bq1[1],0.f);
    q2 = fmaxf(q2+bq1[2],0.f); q3 = fmaxf(q3+bq1[3],0.f);
    float s0 = sigm(q0*wq2[0]+q1*wq2[1]+q2*wq2[2]+q3*wq2[3]+bq2[0]);
    float s1 = sigm(q0*wq2[4]+q1*wq2[5]+q2*wq2[6]+q3*wq2[7]+bq2[1]);
    sQw[mm] = 0.5f*(s0+s1);
    outp[MB_TOT + mm]     = s0;  // boundary
    outp[MB_TOT + 4 + mm] = s1;  // semantic
  }
  __syncthreads();
  float qw_m = sQw[m];
  float T = sQw[0]+sQw[1]+sQw[2]+sQw[3];
  float inv_m = 1.0f/(T - qw_m);
  if (tid < 4){ wsqw[tid] = sQw[tid]; wsinv[tid] = 1.0f/(T - sQw[tid]); }
  {
    const float* xbp = xbsums + (size_t)tid*64;
    float s=0.f;
    for (int p=0;p<64;++p) s += sA[m*64+p]*xbp[p];
    sCm[tid] = qw_m * s * (1.0f/262144.0f);
  }
  __syncthreads();
  {
    int dd = c;
    float acc=0.f;
    for (int cc=0; cc<64; ++cc){
      float Sm = sCm[0*64+cc]+sCm[1*64+cc]+sCm[2*64+cc]+sCm[3*64+cc];
      float em = (Sm - sCm[m*64+cc]) * inv_m;
      acc += em * wf[dd*64+cc];
    }
    sG[tid] = acc + bfv[dd];
  }
  __syncthreads();
  if (tid < 16){
    int mm = tid>>2, k = tid&3;
    float acc=0.f;
    for (int dd=0; dd<64; ++dd) acc += sG[mm*64+dd]*wg1[k*64+dd];
    sGG[tid] = fmaxf(acc + bg1[k], 0.f);
  }
  __syncthreads();
  {
    float s = sGG[m*4+0]*wg2[c*4+0] + sGG[m*4+1]*wg2[c*4+1]
            + sGG[m*4+2]*wg2[c*4+2] + sGG[m*4+3]*wg2[c*4+3] + bg2[c];
    wsgate[tid] = sigm(s);
  }
}

// ---------------- pass 3: coalesced fp32 staging + MFMA + coalesced transposed store ----------
__global__ __launch_bounds__(256) void k_pass3(
    const float* __restrict__ x, const unsigned short* __restrict__ wfb,
    const float* __restrict__ bfv,
    const float* __restrict__ wsa, const float* __restrict__ wsgate,
    const float* __restrict__ wsqw, const float* __restrict__ wsinv,
    float* __restrict__ outp)
{
  __shared__ unsigned int xt[4][32][68];     // [m][cc-pair][vox] bf16 pairs; 16B-aligned rows
  __shared__ unsigned int fusedT[64][34];    // [dd][vox-pair] bf16 pairs
  __shared__ float aCell[4][64];
  __shared__ float gateL[4][64];
  __shared__ __align__(16) float auq[4][64];
  __shared__ float bfL[64];
  __shared__ float A2[4][4];
  int tid = threadIdx.x;
  int b = 4095 - (int)blockIdx.x;     // reversed tile order (L3 reuse from pass1)
  int i = b >> 6, j = b & 63;
  size_t V0 = (size_t)b * 64;
  int w    = tid >> 6;
  int lane = tid & 63;
  int ks   = lane >> 4;
  int r    = lane & 15;
  int vox16 = w << 4;

  const float* xw = x + (size_t)(w*64)*NVOX + V0 + r*4;
  f4 v[16];
#pragma unroll
  for (int rr=0; rr<16; ++rr){
    int cc = ks*16 + rr;
    v[rr] = *reinterpret_cast<const f4*>(xw + (size_t)cc*NVOX);
  }
  aCell[w][lane] = wsa[tid];
  gateL[w][lane] = wsgate[tid];
  if (tid < 64) bfL[tid] = bfv[tid];
#pragma unroll
  for (int rr=0; rr<16; rr+=2){
    u4v pk;
#pragma unroll
    for (int q=0;q<4;++q) pk[q] = cvtpk(v[rr][q], v[rr+1][q]);
    *reinterpret_cast<u4v*>(&xt[w][ks*8 + (rr>>1)][r*4]) = pk;
  }
  __syncthreads();

  if (tid < 16){
    int mm = tid>>2, pz = tid&3;
    float ci = fminf(fmaxf((i+0.5f)*0.0625f-0.5f,0.f),3.f);
    int li=(int)ci; float wi=ci-(float)li; int hiI=li<3?li+1:3;
    float cj = fminf(fmaxf((j+0.5f)*0.0625f-0.5f,0.f),3.f);
    int lj=(int)cj; float wj=cj-(float)lj; int hj=lj<3?lj+1:3;
    A2[mm][pz] = (1.f-wi)*((1.f-wj)*aCell[mm][li*16+lj*4+pz] + wj*aCell[mm][li*16+hj*4+pz])
               + wi*((1.f-wj)*aCell[mm][hiI*16+lj*4+pz] + wj*aCell[mm][hiI*16+hj*4+pz]);
  }
  __syncthreads();
  {
    int mm = tid>>6, z = tid&63;
    float cz = fminf(fmaxf((z+0.5f)*0.0625f-0.5f,0.f),3.f);
    int lz=(int)cz; float wzf=cz-(float)lz; int hz=lz<3?lz+1:3;
    auq[mm][z] = ((1.f-wzf)*A2[mm][lz] + wzf*A2[mm][hz]) * wsqw[mm];
  }
  __syncthreads();

  s8v bfr[4][2];
#pragma unroll
  for (int t=0;t<4;++t)
#pragma unroll
    for (int kk=0;kk<2;++kk)
      bfr[t][kk] = *reinterpret_cast<const s8v*>(&wfb[(t*16 + r)*64 + kk*32 + ks*8]);

  f4 acc[4][4];
#pragma unroll
  for (int mm=0;mm<4;++mm)
#pragma unroll
    for (int t=0;t<4;++t) acc[mm][t] = f4{0.f,0.f,0.f,0.f};

#pragma unroll
  for (int mm=0;mm<4;++mm){
    union { unsigned int u[4]; s8v s; } A0, A1;
#pragma unroll
    for (int q=0;q<4;++q){
      A0.u[q] = xt[mm][ks*4+q][vox16+r];
      A1.u[q] = xt[mm][16+ks*4+q][vox16+r];
    }
#pragma unroll
    for (int t=0;t<4;++t){
      acc[mm][t] = __builtin_amdgcn_mfma_f32_16x16x32_bf16(A0.s, bfr[t][0], acc[mm][t], 0,0,0);
      acc[mm][t] = __builtin_amdgcn_mfma_f32_16x16x32_bf16(A1.s, bfr[t][1], acc[mm][t], 0,0,0);
    }
  }

  f4 aq[4]; float invv[4];
#pragma unroll
  for (int mm=0;mm<4;++mm){
    aq[mm]  = *reinterpret_cast<const f4*>(&auq[mm][vox16 + 4*ks]);
    invv[mm] = wsinv[mm];
  }
  f4 FS[4];
#pragma unroll
  for (int t=0;t<4;++t){
    FS[t] = f4{0.f,0.f,0.f,0.f};
#pragma unroll
    for (int mm=0;mm<4;++mm)
#pragma unroll
      for (int q=0;q<4;++q) FS[t][q] += aq[mm][q]*acc[mm][t][q];
  }

  int g4 = tid >> 4;
  int r4l = tid & 15;
#pragma unroll
  for (int mm=0;mm<4;++mm){
#pragma unroll
    for (int t=0;t<4;++t){
      int dd = t*16 + r;
      float bfvv = bfL[dd];
      float f0 = (FS[t][0] - aq[mm][0]*acc[mm][t][0])*invv[mm] + bfvv;
      float f1 = (FS[t][1] - aq[mm][1]*acc[mm][t][1])*invv[mm] + bfvv;
      float f2 = (FS[t][2] - aq[mm][2]*acc[mm][t][2])*invv[mm] + bfvv;
      float f3 = (FS[t][3] - aq[mm][3]*acc[mm][t][3])*invv[mm] + bfvv;
      u2v pk2;
      pk2.x = cvtpk(f0, f1);
      pk2.y = cvtpk(f2, f3);
      *reinterpret_cast<u2v*>(&fusedT[dd][(vox16 + ks*4)>>1]) = pk2;
    }
    __syncthreads();
#pragma unroll
    for (int rr=0; rr<4; ++rr){
      int dd = rr*16 + g4;
      float g = gateL[mm][dd];
      u4v xu = *reinterpret_cast<const u4v*>(&xt[mm][dd>>1][r4l*4]);
      u2v fu = *reinterpret_cast<const u2v*>(&fusedT[dd][r4l*2]);
      f4 o;
      float x0 = (dd&1) ? bh(xu[0]) : bl(xu[0]);
      float x1 = (dd&1) ? bh(xu[1]) : bl(xu[1]);
      float x2 = (dd&1) ? bh(xu[2]) : bl(xu[2]);
      float x3 = (dd&1) ? bh(xu[3]) : bl(xu[3]);
      o[0] = x0 + g*bl(fu.x);
      o[1] = x1 + g*bh(fu.x);
      o[2] = x2 + g*bl(fu.y);
      o[3] = x3 + g*bh(fu.y);
      *reinterpret_cast<f4*>(outp + (size_t)(mm*64+dd)*NVOX + V0 + r4l*4) = o;
    }
    __syncthreads();
  }
}

extern "C" void kernel_launch(void* const* d_in, const int* in_sizes, int n_in,
                              void* d_out, int out_size, void* d_ws, size_t ws_size,
                              hipStream_t stream){
  const float* x   = (const float*)d_in[0];
  const float* wq1 = (const float*)d_in[1];
  const float* bq1 = (const float*)d_in[2];
  const float* wq2 = (const float*)d_in[3];
  const float* bq2 = (const float*)d_in[4];
  const float* wa1 = (const float*)d_in[5];
  const float* ba1 = (const float*)d_in[6];
  const float* wa2 = (const float*)d_in[7];
  const float* ba2 = (const float*)d_in[8];
  const float* wf  = (const float*)d_in[9];
  const float* bfv = (const float*)d_in[10];
  const float* wg1 = (const float*)d_in[11];
  const float* bg1 = (const float*)d_in[12];
  const float* wg2 = (const float*)d_in[13];
  const float* bg2 = (const float*)d_in[14];
  float* outp = (float*)d_out;
  float* w = (float*)d_ws;
  float* dsums  = w;            // 16384 floats
  float* xbsums = w + 16384;    // 16384 floats
  float* wsa    = w + 32768;    // 256
  float* wsgate = w + 33024;    // 256
  float* wsqw   = w + 33280;    // 4
  float* wsinv  = w + 33284;    // 4
  unsigned short* wfb = (unsigned short*)(w + 33288);  // 4096 bf16
  hipMemsetAsync(w, 0, 32768*sizeof(float), stream);
  hipLaunchKernelGGL(k_pass1, dim3(512), dim3(1024), 0, stream, x, dsums, xbsums);
  hipLaunchKernelGGL(k_pass2, dim3(1), dim3(256), 0, stream, dsums, xbsums,
                     wq1,bq1,wq2,bq2,wa1,ba1,wa2,ba2,wf,bfv,wg1,bg1,wg2,bg2,
                     wsa, wsgate, wsqw, wsinv, wfb, outp);
  hipLaunchKernelGGL(k_pass3, dim3(4096), dim3(256), 0, stream, x, wfb, bfv,
                     wsa, wsgate, wsqw, wsinv, outp);
}

// Round 15
// 269.486 us; speedup vs baseline: 1.0248x; 1.0248x over previous
//
#include <hip/hip_runtime.h>
#include <math.h>

typedef __attribute__((ext_vector_type(4))) float f4;
typedef __attribute__((ext_vector_type(8))) short s8v;   // bf16x8 MFMA fragment
typedef __attribute__((ext_vector_type(4))) unsigned int u4v;
typedef __attribute__((ext_vector_type(2))) unsigned int u2v;

#define NVOX 262144        // 64^3
#define MB_TOT 67108864    // 4*64*NVOX

__device__ __forceinline__ float sigm(float x){ return 1.0f/(1.0f+expf(-x)); }
__device__ __forceinline__ unsigned short f2b(float f){
  unsigned x = __float_as_uint(f);
  return (unsigned short)((x + 0x7fffu + ((x>>16)&1u)) >> 16);
}
__device__ __forceinline__ unsigned cvtpk(float lo, float hi){
  unsigned r;
  asm("v_cvt_pk_bf16_f32 %0, %1, %2" : "=v"(r) : "v"(lo), "v"(hi));
  return r;
}
__device__ __forceinline__ float bl(unsigned u){ return __uint_as_float(u<<16); }
__device__ __forceinline__ float bh(unsigned u){ return __uint_as_float(u & 0xffff0000u); }

// ---------------- pass 1: zero-shuffle, 3-slot register accumulation (fits 64 VGPR) ------
// 512 blocks x 1024 threads; block = (mc = b>>1, half = b&1 -> i in [half*32,+32)).
// KEY FIX vs r14 (which spilled 104 MB): per half, li takes only 2 values -> only THREE
// i-hat slots are ever nonzero (half0: px{0,1,2}, half1: px{1,2,3}). 6+2 named accumulators
// instead of 18 -> ~40 live VGPR, fits the 64-cap at 2 blocks/CU = 32 waves, batch-4 loads,
// zero shuffles/LDS in the loop. Merge: 12+2 LDS atomics into 4 banked copies -> 64 global.

#define LDI(I) (*reinterpret_cast<const f4*>(xp + (size_t)((I)*64 + j)*64 + chunk*4))

// hat weight of global slot K at row I (compile-time after unroll)
#define HWI(I,K) ( \
  ((K) == (((I)<8)?0:(((I)>=56)?3:(((I)-8)>>4)))) ? \
    (1.0f - (((I)<8||(I)>=56)?0.0f:(((I)+0.5f)*0.0625f-0.5f-(float)(((I)<8)?0:(((I)>=56)?3:(((I)-8)>>4)))))) : \
  (((K) == (((I)<8)?0:(((I)>=56)?3:(((I)-8)>>4)))+1) ? \
    (((I)<8||(I)>=56)?0.0f:(((I)+0.5f)*0.0625f-0.5f-(float)(((I)<8)?0:(((I)>=56)?3:(((I)-8)>>4))))) : 0.0f) )

#define BODY(I, V, K0) { \
  float s_ = ((V).x+(V).y)+((V).z+(V).w); \
  float wB_ = (V).x*wq0 + (V).y*wq1 + (V).z*wq2 + (V).w*wq3; \
  float wA_ = s_ - wB_; \
  if ((((I)>>4)&1)==0) blo += s_; else bhi += s_; \
  const float hA_ = HWI(I, (K0)+0); \
  const float hB_ = HWI(I, (K0)+1); \
  const float hC_ = HWI(I, (K0)+2); \
  if (hA_ != 0.0f){ s0L += hA_*wA_; s0H += hA_*wB_; } \
  if (hB_ != 0.0f){ s1L += hB_*wA_; s1H += hB_*wB_; } \
  if (hC_ != 0.0f){ s2L += hC_*wA_; s2H += hC_*wB_; } \
}

#define B4(IB, K0) { \
  f4 v0_ = LDI((IB)+0); \
  f4 v1_ = LDI((IB)+1); \
  f4 v2_ = LDI((IB)+2); \
  f4 v3_ = LDI((IB)+3); \
  BODY((IB)+0, v0_, K0); \
  BODY((IB)+1, v1_, K0); \
  BODY((IB)+2, v2_, K0); \
  BODY((IB)+3, v3_, K0); \
}

#define HALF32(I0, K0) B4(I0,K0) B4((I0)+4,K0) B4((I0)+8,K0) B4((I0)+12,K0) \
                       B4((I0)+16,K0) B4((I0)+20,K0) B4((I0)+24,K0) B4((I0)+28,K0)

__global__ __launch_bounds__(1024) void k_pass1(const float* __restrict__ x,
                                                float* __restrict__ dsums,
                                                float* __restrict__ xbsums){
  __shared__ float xbL[4][64];
  __shared__ float bsL[4][64];
  int tid = threadIdx.x;
  int b = blockIdx.x;
  int mc   = b >> 1;
  int half = b & 1;
  if (tid < 256){ xbL[tid>>6][tid&63]=0.f; bsL[tid>>6][tid&63]=0.f; }
  const float* xp = x + (size_t)mc * NVOX;
  int chunk = tid & 15;
  int j     = tid >> 4;
  // z-weights (lzc uniform within a chunk; chunk*4 quad-aligned to the knots)
  float wq0,wq1,wq2,wq3; int lzc;
  {
    int z0 = chunk*4;
    lzc = (z0<8)?0:((z0>=56)?3:((z0-8)>>4));
    wq0 = (z0  <8||z0  >=56)?0.0f:((z0+0.5f)*0.0625f-0.5f-(float)lzc);
    wq1 = (z0+1<8||z0+1>=56)?0.0f:((z0+1.5f)*0.0625f-0.5f-(float)lzc);
    wq2 = (z0+2<8||z0+2>=56)?0.0f:((z0+2.5f)*0.0625f-0.5f-(float)lzc);
    wq3 = (z0+3<8||z0+3>=56)?0.0f:((z0+3.5f)*0.0625f-0.5f-(float)lzc);
  }
  float cjA, cjB; int lj;
  {
    float cj = fminf(fmaxf((j+0.5f)*0.0625f-0.5f, 0.0f), 3.0f);
    lj = (int)cj; float wj = cj - (float)lj;
    cjA = 1.0f - wj; cjB = wj;
  }
  int jq = j >> 4, kq = chunk >> 2;

  float s0L=0.f,s1L=0.f,s2L=0.f;    // slot accumulators, z-low level (lzc)
  float s0H=0.f,s1H=0.f,s2H=0.f;    // z-high level (lzc+1)
  float blo=0.f, bhi=0.f;

  if (half == 0){ HALF32(0, 0) } else { HALF32(32, 1) }

  __syncthreads();
  int cp = (tid >> 8) & 3;     // 4 banked LDS copies to cut atomic serialization
  int px0 = half;              // global slot base: half0 -> {0,1,2}, half1 -> {1,2,3}
  {
    int p00 = lj*4 + lzc;
#pragma unroll
    for (int k=0; k<3; ++k){
      float vL = (k==0)?s0L:((k==1)?s1L:s2L);
      float vH = (k==0)?s0H:((k==1)?s1H:s2H);
      int base = (px0+k)*16;
      atomicAdd(&xbL[cp][base + p00], cjA*vL);
      if (lzc < 3) atomicAdd(&xbL[cp][base + p00+1], cjA*vH);
      if (lj  < 3){
        atomicAdd(&xbL[cp][base + p00+4], cjB*vL);
        if (lzc < 3) atomicAdd(&xbL[cp][base + p00+5], cjB*vH);
      }
    }
    atomicAdd(&bsL[cp][(half*2  )*16 + jq*4 + kq], blo);
    atomicAdd(&bsL[cp][(half*2+1)*16 + jq*4 + kq], bhi);
  }
  __syncthreads();
  if (tid < 64){
    float xs = xbL[0][tid]+xbL[1][tid]+xbL[2][tid]+xbL[3][tid];
    float bs = bsL[0][tid]+bsL[1][tid]+bsL[2][tid]+bsL[3][tid];
    atomicAdd(&xbsums[(size_t)mc*64 + tid], xs);
    atomicAdd(&dsums [(size_t)mc*64 + tid], bs);
  }
}

// ---------------- pass 2: all tiny MLPs (single block) + wf->bf16 conversion ----------------
__global__ __launch_bounds__(256) void k_pass2(
    const float* __restrict__ dsums, const float* __restrict__ xbsums,
    const float* __restrict__ wq1, const float* __restrict__ bq1,
    const float* __restrict__ wq2, const float* __restrict__ bq2,
    const float* __restrict__ wa1, const float* __restrict__ ba1,
    const float* __restrict__ wa2, const float* __restrict__ ba2,
    const float* __restrict__ wf,  const float* __restrict__ bfv,
    const float* __restrict__ wg1, const float* __restrict__ bg1,
    const float* __restrict__ wg2, const float* __restrict__ bg2,
    float* __restrict__ wsa, float* __restrict__ wsgate,
    float* __restrict__ wsqw, float* __restrict__ wsinv,
    unsigned short* __restrict__ wfb,
    float* __restrict__ outp)
{
  __shared__ float sGap[256];
  __shared__ float sA[256];
  __shared__ float sCm[256];
  __shared__ float sG[256];
  __shared__ float sGG[16];
  __shared__ float sQw[4];
  int tid = threadIdx.x;
  int m = tid>>6, c = tid&63;
  for (int t = tid; t < 4096; t += 256) wfb[t] = f2b(wf[t]);
  {
    float s=0.f;
    const float* dp = dsums + (size_t)tid*64;
    for (int p=0;p<64;++p) s += dp[p];
    sGap[tid] = s * (1.0f/262144.0f);
  }
  {
    int p = c;
    float h0=0,h1=0,h2=0,h3=0;
    for (int cc=0; cc<64; ++cc){
      float dm = dsums[((size_t)(m*64+cc))*64+p] * (1.0f/4096.0f);
      h0 += dm * wa1[0*64+cc];
      h1 += dm * wa1[1*64+cc];
      h2 += dm * wa1[2*64+cc];
      h3 += dm * wa1[3*64+cc];
    }
    h0 = fmaxf(h0 + ba1[0], 0.f);
    h1 = fmaxf(h1 + ba1[1], 0.f);
    h2 = fmaxf(h2 + ba1[2], 0.f);
    h3 = fmaxf(h3 + ba1[3], 0.f);
    float s = h0*wa2[0] + h1*wa2[1] + h2*wa2[2] + h3*wa2[3] + ba2[0];
    float aa = sigm(s);
    sA[tid] = aa;
    wsa[tid] = aa;
  }
  __syncthreads();
  if (tid < 4){
    int mm = tid;
    float q0=0,q1=0,q2=0,q3=0;
    for (int cc=0; cc<64; ++cc){
      float g = sGap[mm*64+cc];
      q0 += g*wq1[0*64+cc];
      q1 += g*wq1[1*64+cc];
      q2 += g*wq1[2*64+cc];
      q3 += g*wq1[3*64+cc];
    }
    q0 = fmaxf(q0+bq1[0],0.f); q1 = fmaxf(q1+bq1[1],0.f);
    q2 = fmaxf(q2+bq1[2],0.f); q3 = fmaxf(q3+bq1[3],0.f);
    float s0 = sigm(q0*wq2[0]+q1*wq2[1]+q2*wq2[2]+q3*wq2[3]+bq2[0]);
    float s1 = sigm(q0*wq2[4]+q1*wq2[5]+q2*wq2[6]+q3*wq2[7]+bq2[1]);
    sQw[mm] = 0.5f*(s0+s1);
    outp[MB_TOT + mm]     = s0;  // boundary
    outp[MB_TOT + 4 + mm] = s1;  // semantic
  }
  __syncthreads();
  float qw_m = sQw[m];
  float T = sQw[0]+sQw[1]+sQw[2]+sQw[3];
  float inv_m = 1.0f/(T - qw_m);
  if (tid < 4){ wsqw[tid] = sQw[tid]; wsinv[tid] = 1.0f/(T - sQw[tid]); }
  {
    const float* xbp = xbsums + (size_t)tid*64;
    float s=0.f;
    for (int p=0;p<64;++p) s += sA[m*64+p]*xbp[p];
    sCm[tid] = qw_m * s * (1.0f/262144.0f);
  }
  __syncthreads();
  {
    int dd = c;
    float acc=0.f;
    for (int cc=0; cc<64; ++cc){
      float Sm = sCm[0*64+cc]+sCm[1*64+cc]+sCm[2*64+cc]+sCm[3*64+cc];
      float em = (Sm - sCm[m*64+cc]) * inv_m;
      acc += em * wf[dd*64+cc];
    }
    sG[tid] = acc + bfv[dd];
  }
  __syncthreads();
  if (tid < 16){
    int mm = tid>>2, k = tid&3;
    float acc=0.f;
    for (int dd=0; dd<64; ++dd) acc += sG[mm*64+dd]*wg1[k*64+dd];
    sGG[tid] = fmaxf(acc + bg1[k], 0.f);
  }
  __syncthreads();
  {
    float s = sGG[m*4+0]*wg2[c*4+0] + sGG[m*4+1]*wg2[c*4+1]
            + sGG[m*4+2]*wg2[c*4+2] + sGG[m*4+3]*wg2[c*4+3] + bg2[c];
    wsgate[tid] = sigm(s);
  }
}

// ---------------- pass 3: coalesced fp32 staging + MFMA + coalesced transposed store ----------
__global__ __launch_bounds__(256) void k_pass3(
    const float* __restrict__ x, const unsigned short* __restrict__ wfb,
    const float* __restrict__ bfv,
    const float* __restrict__ wsa, const float* __restrict__ wsgate,
    const float* __restrict__ wsqw, const float* __restrict__ wsinv,
    float* __restrict__ outp)
{
  __shared__ unsigned int xt[4][32][68];     // [m][cc-pair][vox] bf16 pairs; 16B-aligned rows
  __shared__ unsigned int fusedT[64][34];    // [dd][vox-pair] bf16 pairs
  __shared__ float aCell[4][64];
  __shared__ float gateL[4][64];
  __shared__ __align__(16) float auq[4][64];
  __shared__ float bfL[64];
  __shared__ float A2[4][4];
  int tid = threadIdx.x;
  int b = 4095 - (int)blockIdx.x;     // reversed tile order (L3 reuse from pass1)
  int i = b >> 6, j = b & 63;
  size_t V0 = (size_t)b * 64;
  int w    = tid >> 6;
  int lane = tid & 63;
  int ks   = lane >> 4;
  int r    = lane & 15;
  int vox16 = w << 4;

  const float* xw = x + (size_t)(w*64)*NVOX + V0 + r*4;
  f4 v[16];
#pragma unroll
  for (int rr=0; rr<16; ++rr){
    int cc = ks*16 + rr;
    v[rr] = *reinterpret_cast<const f4*>(xw + (size_t)cc*NVOX);
  }
  aCell[w][lane] = wsa[tid];
  gateL[w][lane] = wsgate[tid];
  if (tid < 64) bfL[tid] = bfv[tid];
#pragma unroll
  for (int rr=0; rr<16; rr+=2){
    u4v pk;
#pragma unroll
    for (int q=0;q<4;++q) pk[q] = cvtpk(v[rr][q], v[rr+1][q]);
    *reinterpret_cast<u4v*>(&xt[w][ks*8 + (rr>>1)][r*4]) = pk;
  }
  __syncthreads();

  if (tid < 16){
    int mm = tid>>2, pz = tid&3;
    float ci = fminf(fmaxf((i+0.5f)*0.0625f-0.5f,0.f),3.f);
    int li=(int)ci; float wi=ci-(float)li; int hiI=li<3?li+1:3;
    float cj = fminf(fmaxf((j+0.5f)*0.0625f-0.5f,0.f),3.f);
    int lj=(int)cj; float wj=cj-(float)lj; int hj=lj<3?lj+1:3;
    A2[mm][pz] = (1.f-wi)*((1.f-wj)*aCell[mm][li*16+lj*4+pz] + wj*aCell[mm][li*16+hj*4+pz])
               + wi*((1.f-wj)*aCell[mm][hiI*16+lj*4+pz] + wj*aCell[mm][hiI*16+hj*4+pz]);
  }
  __syncthreads();
  {
    int mm = tid>>6, z = tid&63;
    float cz = fminf(fmaxf((z+0.5f)*0.0625f-0.5f,0.f),3.f);
    int lz=(int)cz; float wzf=cz-(float)lz; int hz=lz<3?lz+1:3;
    auq[mm][z] = ((1.f-wzf)*A2[mm][lz] + wzf*A2[mm][hz]) * wsqw[mm];
  }
  __syncthreads();

  s8v bfr[4][2];
#pragma unroll
  for (int t=0;t<4;++t)
#pragma unroll
    for (int kk=0;kk<2;++kk)
      bfr[t][kk] = *reinterpret_cast<const s8v*>(&wfb[(t*16 + r)*64 + kk*32 + ks*8]);

  f4 acc[4][4];
#pragma unroll
  for (int mm=0;mm<4;++mm)
#pragma unroll
    for (int t=0;t<4;++t) acc[mm][t] = f4{0.f,0.f,0.f,0.f};

#pragma unroll
  for (int mm=0;mm<4;++mm){
    union { unsigned int u[4]; s8v s; } A0, A1;
#pragma unroll
    for (int q=0;q<4;++q){
      A0.u[q] = xt[mm][ks*4+q][vox16+r];
      A1.u[q] = xt[mm][16+ks*4+q][vox16+r];
    }
#pragma unroll
    for (int t=0;t<4;++t){
      acc[mm][t] = __builtin_amdgcn_mfma_f32_16x16x32_bf16(A0.s, bfr[t][0], acc[mm][t], 0,0,0);
      acc[mm][t] = __builtin_amdgcn_mfma_f32_16x16x32_bf16(A1.s, bfr[t][1], acc[mm][t], 0,0,0);
    }
  }

  f4 aq[4]; float invv[4];
#pragma unroll
  for (int mm=0;mm<4;++mm){
    aq[mm]  = *reinterpret_cast<const f4*>(&auq[mm][vox16 + 4*ks]);
    invv[mm] = wsinv[mm];
  }
  f4 FS[4];
#pragma unroll
  for (int t=0;t<4;++t){
    FS[t] = f4{0.f,0.f,0.f,0.f};
#pragma unroll
    for (int mm=0;mm<4;++mm)
#pragma unroll
      for (int q=0;q<4;++q) FS[t][q] += aq[mm][q]*acc[mm][t][q];
  }

  int g4 = tid >> 4;
  int r4l = tid & 15;
#pragma unroll
  for (int mm=0;mm<4;++mm){
#pragma unroll
    for (int t=0;t<4;++t){
      int dd = t*16 + r;
      float bfvv = bfL[dd];
      float f0 = (FS[t][0] - aq[mm][0]*acc[mm][t][0])*invv[mm] + bfvv;
      float f1 = (FS[t][1] - aq[mm][1]*acc[mm][t][1])*invv[mm] + bfvv;
      float f2 = (FS[t][2] - aq[mm][2]*acc[mm][t][2])*invv[mm] + bfvv;
      float f3 = (FS[t][3] - aq[mm][3]*acc[mm][t][3])*invv[mm] + bfvv;
      u2v pk2;
      pk2.x = cvtpk(f0, f1);
      pk2.y = cvtpk(f2, f3);
      *reinterpret_cast<u2v*>(&fusedT[dd][(vox16 + ks*4)>>1]) = pk2;
    }
    __syncthreads();
#pragma unroll
    for (int rr=0; rr<4; ++rr){
      int dd = rr*16 + g4;
      float g = gateL[mm][dd];
      u4v xu = *reinterpret_cast<const u4v*>(&xt[mm][dd>>1][r4l*4]);
      u2v fu = *reinterpret_cast<const u2v*>(&fusedT[dd][r4l*2]);
      f4 o;
      float x0 = (dd&1) ? bh(xu[0]) : bl(xu[0]);
      float x1 = (dd&1) ? bh(xu[1]) : bl(xu[1]);
      float x2 = (dd&1) ? bh(xu[2]) : bl(xu[2]);
      float x3 = (dd&1) ? bh(xu[3]) : bl(xu[3]);
      o[0] = x0 + g*bl(fu.x);
      o[1] = x1 + g*bh(fu.x);
      o[2] = x2 + g*bl(fu.y);
      o[3] = x3 + g*bh(fu.y);
      *reinterpret_cast<f4*>(outp + (size_t)(mm*64+dd)*NVOX + V0 + r4l*4) = o;
    }
    __syncthreads();
  }
}

extern "C" void kernel_launch(void* const* d_in, const int* in_sizes, int n_in,
                              void* d_out, int out_size, void* d_ws, size_t ws_size,
                              hipStream_t stream){
  const float* x   = (const float*)d_in[0];
  const float* wq1 = (const float*)d_in[1];
  const float* bq1 = (const float*)d_in[2];
  const float* wq2 = (const float*)d_in[3];
  const float* bq2 = (const float*)d_in[4];
  const float* wa1 = (const float*)d_in[5];
  const float* ba1 = (const float*)d_in[6];
  const float* wa2 = (const float*)d_in[7];
  const float* ba2 = (const float*)d_in[8];
  const float* wf  = (const float*)d_in[9];
  const float* bfv = (const float*)d_in[10];
  const float* wg1 = (const float*)d_in[11];
  const float* bg1 = (const float*)d_in[12];
  const float* wg2 = (const float*)d_in[13];
  const float* bg2 = (const float*)d_in[14];
  float* outp = (float*)d_out;
  float* w = (float*)d_ws;
  float* dsums  = w;            // 16384 floats
  float* xbsums = w + 16384;    // 16384 floats
  float* wsa    = w + 32768;    // 256
  float* wsgate = w + 33024;    // 256
  float* wsqw   = w + 33280;    // 4
  float* wsinv  = w + 33284;    // 4
  unsigned short* wfb = (unsigned short*)(w + 33288);  // 4096 bf16
  hipMemsetAsync(w, 0, 32768*sizeof(float), stream);
  hipLaunchKernelGGL(k_pass1, dim3(512), dim3(1024), 0, stream, x, dsums, xbsums);
  hipLaunchKernelGGL(k_pass2, dim3(1), dim3(256), 0, stream, dsums, xbsums,
                     wq1,bq1,wq2,bq2,wa1,ba1,wa2,ba2,wf,bfv,wg1,bg1,wg2,bg2,
                     wsa, wsgate, wsqw, wsinv, wfb, outp);
  hipLaunchKernelGGL(k_pass3, dim3(4096), dim3(256), 0, stream, x, wfb, bfv,
                     wsa, wsgate, wsqw, wsinv, outp);
}

// Round 16
// 223.660 us; speedup vs baseline: 1.2348x; 1.2049x over previous
//
#include <hip/hip_runtime.h>
#include <math.h>

typedef __attribute__((ext_vector_type(4))) float f4;
typedef __attribute__((ext_vector_type(8))) short s8v;   // bf16x8 MFMA fragment
typedef __attribute__((ext_vector_type(4))) unsigned int u4v;
typedef __attribute__((ext_vector_type(2))) unsigned int u2v;

#define NVOX 262144        // 64^3
#define MB_TOT 67108864    // 4*64*NVOX

__device__ __forceinline__ float sigm(float x){ return 1.0f/(1.0f+expf(-x)); }
__device__ __forceinline__ unsigned short f2b(float f){
  unsigned x = __float_as_uint(f);
  return (unsigned short)((x + 0x7fffu + ((x>>16)&1u)) >> 16);
}
__device__ __forceinline__ unsigned cvtpk(float lo, float hi){
  unsigned r;
  asm("v_cvt_pk_bf16_f32 %0, %1, %2" : "=v"(r) : "v"(lo), "v"(hi));
  return r;
}
__device__ __forceinline__ float bl(unsigned u){ return __uint_as_float(u<<16); }
__device__ __forceinline__ float bh(unsigned u){ return __uint_as_float(u & 0xffff0000u); }

// ---------------- pass 1: 512-thr quarter-plane blocks, bounded pipeline, zero shuffles ----
// 2048 blocks x 512 threads; block = (mc = b>>3, q = (b>>1)&3 -> i in [q*16,+16), jh = b&1).
// thread: chunk = tid&15 (z-quad), j = jh*32 + (tid>>4).
// Register pressure is ARCHITECTURALLY bounded (r14/r15 spilled via load-hoisting at the
// 1024-thread 64-VGPR cap): 512-thr blocks + "#pragma unroll 1" outer loop (4 rows/iter,
// batch-4 loads) cap in-flight data at 16 VGPR. Hat weights computed at runtime from
// integer i (~20 VALU/row, 4x under the VALU-vs-HBM break-even). Per quarter only 3 i-hat
// slots are reachable -> 6+1 named accumulators. ~49 VGPR -> 4 blocks/CU = 32 waves.
__global__ __launch_bounds__(512) void k_pass1(const float* __restrict__ x,
                                               float* __restrict__ dsums,
                                               float* __restrict__ xbsums){
  __shared__ float xbL[4][64];
  __shared__ float bsL[4][64];
  int tid = threadIdx.x;
  int b = blockIdx.x;
  int mc = b >> 3;
  int q  = (b >> 1) & 3;
  int jh = b & 1;
  if (tid < 256){ xbL[tid>>6][tid&63]=0.f; bsL[tid>>6][tid&63]=0.f; }
  const float* xp = x + (size_t)mc * NVOX;
  int chunk = tid & 15;
  int j     = jh*32 + (tid >> 4);
  // z-weights (lzc uniform within a chunk; chunk*4 quad-aligned to knots 8/24/40/56)
  float wq0,wq1,wq2,wq3; int lzc;
  {
    int z0 = chunk*4;
    lzc = (z0<8)?0:((z0>=56)?3:((z0-8)>>4));
    wq0 = (z0  <8||z0  >=56)?0.0f:((z0+0.5f)*0.0625f-0.5f-(float)lzc);
    wq1 = (z0+1<8||z0+1>=56)?0.0f:((z0+1.5f)*0.0625f-0.5f-(float)lzc);
    wq2 = (z0+2<8||z0+2>=56)?0.0f:((z0+2.5f)*0.0625f-0.5f-(float)lzc);
    wq3 = (z0+3<8||z0+3>=56)?0.0f:((z0+3.5f)*0.0625f-0.5f-(float)lzc);
  }
  float cjA, cjB; int lj;
  {
    float cj = fminf(fmaxf((j+0.5f)*0.0625f-0.5f, 0.0f), 3.0f);
    lj = (int)cj; float wj = cj - (float)lj;
    cjA = 1.0f - wj; cjB = wj;
  }
  int jq = j >> 4, kq = chunk >> 2;
  int base = (q==0)?0:((q==1)?0:((q==2)?1:2));   // min li in this quarter

  float s0L=0.f,s1L=0.f,s2L=0.f;
  float s0H=0.f,s1H=0.f,s2H=0.f;
  float bacc=0.f;

#pragma unroll 1
  for (int g=0; g<4; ++g){
    int i0 = q*16 + g*4;
    const float* p0 = xp + (size_t)(i0*64 + j)*64 + chunk*4;
    f4 v0 = *reinterpret_cast<const f4*>(p0);
    f4 v1 = *reinterpret_cast<const f4*>(p0 + 4096);
    f4 v2 = *reinterpret_cast<const f4*>(p0 + 8192);
    f4 v3 = *reinterpret_cast<const f4*>(p0 + 12288);
#pragma unroll
    for (int s=0; s<4; ++s){
      f4 v = (s==0)?v0:((s==1)?v1:((s==2)?v2:v3));
      int i = i0 + s;
      float sm = (v.x+v.y)+(v.z+v.w);
      float wB = v.x*wq0 + v.y*wq1 + v.z*wq2 + v.w*wq3;
      float wA = sm - wB;
      bacc += sm;
      int li = (i<8)?0:((i>=56)?3:((i-8)>>4));
      float wi = (i<8||i>=56)?0.0f:((i+0.5f)*0.0625f-0.5f-(float)li);
      int a = li - base;                 // 0 or 1 in every quarter
      float hA = 1.0f - wi, hB = wi;
      float h0 = (a==0)?hA:0.0f;
      float h1 = (a==1)?hA:hB;           // a==0 -> slot1 gets hB; a==1 -> slot1 gets hA
      float h2 = (a==1)?hB:0.0f;
      s0L += h0*wA; s0H += h0*wB;
      s1L += h1*wA; s1H += h1*wB;
      s2L += h2*wA; s2H += h2*wB;
    }
  }

  __syncthreads();   // zero-init visible before atomics
  int cp = (tid >> 7) & 3;
  {
    int p00 = lj*4 + lzc;
#pragma unroll
    for (int k=0; k<3; ++k){
      int px = base + k;
      if (px < 4){
        float vL = (k==0)?s0L:((k==1)?s1L:s2L);
        float vH = (k==0)?s0H:((k==1)?s1H:s2H);
        int b16 = px*16;
        atomicAdd(&xbL[cp][b16 + p00], cjA*vL);
        if (lzc < 3) atomicAdd(&xbL[cp][b16 + p00+1], cjA*vH);
        if (lj  < 3){
          atomicAdd(&xbL[cp][b16 + p00+4], cjB*vL);
          if (lzc < 3) atomicAdd(&xbL[cp][b16 + p00+5], cjB*vH);
        }
      }
    }
    atomicAdd(&bsL[cp][q*16 + jq*4 + kq], bacc);
  }
  __syncthreads();
  if (tid < 64){
    float xs = xbL[0][tid]+xbL[1][tid]+xbL[2][tid]+xbL[3][tid];
    float bs = bsL[0][tid]+bsL[1][tid]+bsL[2][tid]+bsL[3][tid];
    atomicAdd(&xbsums[(size_t)mc*64 + tid], xs);
    atomicAdd(&dsums [(size_t)mc*64 + tid], bs);
  }
}

// ---------------- pass 2: all tiny MLPs (single block) + wf->bf16 conversion ----------------
__global__ __launch_bounds__(256) void k_pass2(
    const float* __restrict__ dsums, const float* __restrict__ xbsums,
    const float* __restrict__ wq1, const float* __restrict__ bq1,
    const float* __restrict__ wq2, const float* __restrict__ bq2,
    const float* __restrict__ wa1, const float* __restrict__ ba1,
    const float* __restrict__ wa2, const float* __restrict__ ba2,
    const float* __restrict__ wf,  const float* __restrict__ bfv,
    const float* __restrict__ wg1, const float* __restrict__ bg1,
    const float* __restrict__ wg2, const float* __restrict__ bg2,
    float* __restrict__ wsa, float* __restrict__ wsgate,
    float* __restrict__ wsqw, float* __restrict__ wsinv,
    unsigned short* __restrict__ wfb,
    float* __restrict__ outp)
{
  __shared__ float sGap[256];
  __shared__ float sA[256];
  __shared__ float sCm[256];
  __shared__ float sG[256];
  __shared__ float sGG[16];
  __shared__ float sQw[4];
  int tid = threadIdx.x;
  int m = tid>>6, c = tid&63;
  for (int t = tid; t < 4096; t += 256) wfb[t] = f2b(wf[t]);
  {
    float s=0.f;
    const float* dp = dsums + (size_t)tid*64;
    for (int p=0;p<64;++p) s += dp[p];
    sGap[tid] = s * (1.0f/262144.0f);
  }
  {
    int p = c;
    float h0=0,h1=0,h2=0,h3=0;
    for (int cc=0; cc<64; ++cc){
      float dm = dsums[((size_t)(m*64+cc))*64+p] * (1.0f/4096.0f);
      h0 += dm * wa1[0*64+cc];
      h1 += dm * wa1[1*64+cc];
      h2 += dm * wa1[2*64+cc];
      h3 += dm * wa1[3*64+cc];
    }
    h0 = fmaxf(h0 + ba1[0], 0.f);
    h1 = fmaxf(h1 + ba1[1], 0.f);
    h2 = fmaxf(h2 + ba1[2], 0.f);
    h3 = fmaxf(h3 + ba1[3], 0.f);
    float s = h0*wa2[0] + h1*wa2[1] + h2*wa2[2] + h3*wa2[3] + ba2[0];
    float aa = sigm(s);
    sA[tid] = aa;
    wsa[tid] = aa;
  }
  __syncthreads();
  if (tid < 4){
    int mm = tid;
    float q0=0,q1=0,q2=0,q3=0;
    for (int cc=0; cc<64; ++cc){
      float g = sGap[mm*64+cc];
      q0 += g*wq1[0*64+cc];
      q1 += g*wq1[1*64+cc];
      q2 += g*wq1[2*64+cc];
      q3 += g*wq1[3*64+cc];
    }
    q0 = fmaxf(q0+bq1[0],0.f); q1 = fmaxf(q1+bq1[1],0.f);
    q2 = fmaxf(q2+bq1[2],0.f); q3 = fmaxf(q3+bq1[3],0.f);
    float s0 = sigm(q0*wq2[0]+q1*wq2[1]+q2*wq2[2]+q3*wq2[3]+bq2[0]);
    float s1 = sigm(q0*wq2[4]+q1*wq2[5]+q2*wq2[6]+q3*wq2[7]+bq2[1]);
    sQw[mm] = 0.5f*(s0+s1);
    outp[MB_TOT + mm]     = s0;  // boundary
    outp[MB_TOT + 4 + mm] = s1;  // semantic
  }
  __syncthreads();
  float qw_m = sQw[m];
  float T = sQw[0]+sQw[1]+sQw[2]+sQw[3];
  float inv_m = 1.0f/(T - qw_m);
  if (tid < 4){ wsqw[tid] = sQw[tid]; wsinv[tid] = 1.0f/(T - sQw[tid]); }
  {
    const float* xbp = xbsums + (size_t)tid*64;
    float s=0.f;
    for (int p=0;p<64;++p) s += sA[m*64+p]*xbp[p];
    sCm[tid] = qw_m * s * (1.0f/262144.0f);
  }
  __syncthreads();
  {
    int dd = c;
    float acc=0.f;
    for (int cc=0; cc<64; ++cc){
      float Sm = sCm[0*64+cc]+sCm[1*64+cc]+sCm[2*64+cc]+sCm[3*64+cc];
      float em = (Sm - sCm[m*64+cc]) * inv_m;
      acc += em * wf[dd*64+cc];
    }
    sG[tid] = acc + bfv[dd];
  }
  __syncthreads();
  if (tid < 16){
    int mm = tid>>2, k = tid&3;
    float acc=0.f;
    for (int dd=0; dd<64; ++dd) acc += sG[mm*64+dd]*wg1[k*64+dd];
    sGG[tid] = fmaxf(acc + bg1[k], 0.f);
  }
  __syncthreads();
  {
    float s = sGG[m*4+0]*wg2[c*4+0] + sGG[m*4+1]*wg2[c*4+1]
            + sGG[m*4+2]*wg2[c*4+2] + sGG[m*4+3]*wg2[c*4+3] + bg2[c];
    wsgate[tid] = sigm(s);
  }
}

// ---------------- pass 3: coalesced fp32 staging + MFMA + coalesced transposed store ----------
__global__ __launch_bounds__(256) void k_pass3(
    const float* __restrict__ x, const unsigned short* __restrict__ wfb,
    const float* __restrict__ bfv,
    const float* __restrict__ wsa, const float* __restrict__ wsgate,
    const float* __restrict__ wsqw, const float* __restrict__ wsinv,
    float* __restrict__ outp)
{
  __shared__ unsigned int xt[4][32][68];     // [m][cc-pair][vox] bf16 pairs; 16B-aligned rows
  __shared__ unsigned int fusedT[64][34];    // [dd][vox-pair] bf16 pairs
  __shared__ float aCell[4][64];
  __shared__ float gateL[4][64];
  __shared__ __align__(16) float auq[4][64];
  __shared__ float bfL[64];
  __shared__ float A2[4][4];
  int tid = threadIdx.x;
  int b = 4095 - (int)blockIdx.x;     // reversed tile order (L3 reuse from pass1)
  int i = b >> 6, j = b & 63;
  size_t V0 = (size_t)b * 64;
  int w    = tid >> 6;
  int lane = tid & 63;
  int ks   = lane >> 4;
  int r    = lane & 15;
  int vox16 = w << 4;

  const float* xw = x + (size_t)(w*64)*NVOX + V0 + r*4;
  f4 v[16];
#pragma unroll
  for (int rr=0; rr<16; ++rr){
    int cc = ks*16 + rr;
    v[rr] = *reinterpret_cast<const f4*>(xw + (size_t)cc*NVOX);
  }
  aCell[w][lane] = wsa[tid];
  gateL[w][lane] = wsgate[tid];
  if (tid < 64) bfL[tid] = bfv[tid];
#pragma unroll
  for (int rr=0; rr<16; rr+=2){
    u4v pk;
#pragma unroll
    for (int q2=0;q2<4;++q2) pk[q2] = cvtpk(v[rr][q2], v[rr+1][q2]);
    *reinterpret_cast<u4v*>(&xt[w][ks*8 + (rr>>1)][r*4]) = pk;
  }
  __syncthreads();

  if (tid < 16){
    int mm = tid>>2, pz = tid&3;
    float ci = fminf(fmaxf((i+0.5f)*0.0625f-0.5f,0.f),3.f);
    int li=(int)ci; float wi=ci-(float)li; int hiI=li<3?li+1:3;
    float cj = fminf(fmaxf((j+0.5f)*0.0625f-0.5f,0.f),3.f);
    int lj=(int)cj; float wj=cj-(float)lj; int hj=lj<3?lj+1:3;
    A2[mm][pz] = (1.f-wi)*((1.f-wj)*aCell[mm][li*16+lj*4+pz] + wj*aCell[mm][li*16+hj*4+pz])
               + wi*((1.f-wj)*aCell[mm][hiI*16+lj*4+pz] + wj*aCell[mm][hiI*16+hj*4+pz]);
  }
  __syncthreads();
  {
    int mm = tid>>6, z = tid&63;
    float cz = fminf(fmaxf((z+0.5f)*0.0625f-0.5f,0.f),3.f);
    int lz=(int)cz; float wzf=cz-(float)lz; int hz=lz<3?lz+1:3;
    auq[mm][z] = ((1.f-wzf)*A2[mm][lz] + wzf*A2[mm][hz]) * wsqw[mm];
  }
  __syncthreads();

  s8v bfr[4][2];
#pragma unroll
  for (int t=0;t<4;++t)
#pragma unroll
    for (int kk=0;kk<2;++kk)
      bfr[t][kk] = *reinterpret_cast<const s8v*>(&wfb[(t*16 + r)*64 + kk*32 + ks*8]);

  f4 acc[4][4];
#pragma unroll
  for (int mm=0;mm<4;++mm)
#pragma unroll
    for (int t=0;t<4;++t) acc[mm][t] = f4{0.f,0.f,0.f,0.f};

#pragma unroll
  for (int mm=0;mm<4;++mm){
    union { unsigned int u[4]; s8v s; } A0, A1;
#pragma unroll
    for (int q2=0;q2<4;++q2){
      A0.u[q2] = xt[mm][ks*4+q2][vox16+r];
      A1.u[q2] = xt[mm][16+ks*4+q2][vox16+r];
    }
#pragma unroll
    for (int t=0;t<4;++t){
      acc[mm][t] = __builtin_amdgcn_mfma_f32_16x16x32_bf16(A0.s, bfr[t][0], acc[mm][t], 0,0,0);
      acc[mm][t] = __builtin_amdgcn_mfma_f32_16x16x32_bf16(A1.s, bfr[t][1], acc[mm][t], 0,0,0);
    }
  }

  f4 aq[4]; float invv[4];
#pragma unroll
  for (int mm=0;mm<4;++mm){
    aq[mm]  = *reinterpret_cast<const f4*>(&auq[mm][vox16 + 4*ks]);
    invv[mm] = wsinv[mm];
  }
  f4 FS[4];
#pragma unroll
  for (int t=0;t<4;++t){
    FS[t] = f4{0.f,0.f,0.f,0.f};
#pragma unroll
    for (int mm=0;mm<4;++mm)
#pragma unroll
      for (int q2=0;q2<4;++q2) FS[t][q2] += aq[mm][q2]*acc[mm][t][q2];
  }

  int g4 = tid >> 4;
  int r4l = tid & 15;
#pragma unroll
  for (int mm=0;mm<4;++mm){
#pragma unroll
    for (int t=0;t<4;++t){
      int dd = t*16 + r;
      float bfvv = bfL[dd];
      float f0 = (FS[t][0] - aq[mm][0]*acc[mm][t][0])*invv[mm] + bfvv;
      float f1 = (FS[t][1] - aq[mm][1]*acc[mm][t][1])*invv[mm] + bfvv;
      float f2 = (FS[t][2] - aq[mm][2]*acc[mm][t][2])*invv[mm] + bfvv;
      float f3 = (FS[t][3] - aq[mm][3]*acc[mm][t][3])*invv[mm] + bfvv;
      u2v pk2;
      pk2.x = cvtpk(f0, f1);
      pk2.y = cvtpk(f2, f3);
      *reinterpret_cast<u2v*>(&fusedT[dd][(vox16 + ks*4)>>1]) = pk2;
    }
    __syncthreads();
#pragma unroll
    for (int rr=0; rr<4; ++rr){
      int dd = rr*16 + g4;
      float g = gateL[mm][dd];
      u4v xu = *reinterpret_cast<const u4v*>(&xt[mm][dd>>1][r4l*4]);
      u2v fu = *reinterpret_cast<const u2v*>(&fusedT[dd][r4l*2]);
      f4 o;
      float x0 = (dd&1) ? bh(xu[0]) : bl(xu[0]);
      float x1 = (dd&1) ? bh(xu[1]) : bl(xu[1]);
      float x2 = (dd&1) ? bh(xu[2]) : bl(xu[2]);
      float x3 = (dd&1) ? bh(xu[3]) : bl(xu[3]);
      o[0] = x0 + g*bl(fu.x);
      o[1] = x1 + g*bh(fu.x);
      o[2] = x2 + g*bl(fu.y);
      o[3] = x3 + g*bh(fu.y);
      *reinterpret_cast<f4*>(outp + (size_t)(mm*64+dd)*NVOX + V0 + r4l*4) = o;
    }
    __syncthreads();
  }
}

extern "C" void kernel_launch(void* const* d_in, const int* in_sizes, int n_in,
                              void* d_out, int out_size, void* d_ws, size_t ws_size,
                              hipStream_t stream){
  const float* x   = (const float*)d_in[0];
  const float* wq1 = (const float*)d_in[1];
  const float* bq1 = (const float*)d_in[2];
  const float* wq2 = (const float*)d_in[3];
  const float* bq2 = (const float*)d_in[4];
  const float* wa1 = (const float*)d_in[5];
  const float* ba1 = (const float*)d_in[6];
  const float* wa2 = (const float*)d_in[7];
  const float* ba2 = (const float*)d_in[8];
  const float* wf  = (const float*)d_in[9];
  const float* bfv = (const float*)d_in[10];
  const float* wg1 = (const float*)d_in[11];
  const float* bg1 = (const float*)d_in[12];
  const float* wg2 = (const float*)d_in[13];
  const float* bg2 = (const float*)d_in[14];
  float* outp = (float*)d_out;
  float* w = (float*)d_ws;
  float* dsums  = w;            // 16384 floats
  float* xbsums = w + 16384;    // 16384 floats
  float* wsa    = w + 32768;    // 256
  float* wsgate = w + 33024;    // 256
  float* wsqw   = w + 33280;    // 4
  float* wsinv  = w + 33284;    // 4
  unsigned short* wfb = (unsigned short*)(w + 33288);  // 4096 bf16
  hipMemsetAsync(w, 0, 32768*sizeof(float), stream);
  hipLaunchKernelGGL(k_pass1, dim3(2048), dim3(512), 0, stream, x, dsums, xbsums);
  hipLaunchKernelGGL(k_pass2, dim3(1), dim3(256), 0, stream, dsums, xbsums,
                     wq1,bq1,wq2,bq2,wa1,ba1,wa2,ba2,wf,bfv,wg1,bg1,wg2,bg2,
                     wsa, wsgate, wsqw, wsinv, wfb, outp);
  hipLaunchKernelGGL(k_pass3, dim3(4096), dim3(256), 0, stream, x, wfb, bfv,
                     wsa, wsgate, wsqw, wsinv, outp);
}

// Round 17
// 198.170 us; speedup vs baseline: 1.3936x; 1.1286x over previous
//
#include <hip/hip_runtime.h>
#include <math.h>

typedef __attribute__((ext_vector_type(4))) float f4;
typedef __attribute__((ext_vector_type(8))) short s8v;   // bf16x8 MFMA fragment
typedef __attribute__((ext_vector_type(4))) unsigned int u4v;
typedef __attribute__((ext_vector_type(2))) unsigned int u2v;

#define NVOX 262144        // 64^3
#define MB_TOT 67108864    // 4*64*NVOX

__device__ __forceinline__ float sigm(float x){ return 1.0f/(1.0f+expf(-x)); }
__device__ __forceinline__ unsigned short f2b(float f){
  unsigned x = __float_as_uint(f);
  return (unsigned short)((x + 0x7fffu + ((x>>16)&1u)) >> 16);
}
__device__ __forceinline__ unsigned cvtpk(float lo, float hi){
  unsigned r;
  asm("v_cvt_pk_bf16_f32 %0, %1, %2" : "=v"(r) : "v"(lo), "v"(hi));
  return r;
}
__device__ __forceinline__ float bl(unsigned u){ return __uint_as_float(u<<16); }
__device__ __forceinline__ float bh(unsigned u){ return __uint_as_float(u & 0xffff0000u); }

// ---------------- pass 1: r13 exact — best measured (total 197us) ----------------
// 512 blocks x 1024 threads; block = (mc = b>>1, half = b&1 -> rounds {2*half, 2*half+1}).
// thread: chunk = tid&15 (z-quad), j = tid>>4. Wave-load = 1KB contiguous, batch-4,
// 16 loads/round streamed. 2 blocks/CU = 32 waves. Butterfly z-collapse (shuffles) keeps
// VGPR at 64 without spill — register-accumulator variants (r14-r16) all spilled or
// serialized; this corner of the {batch, registers, occupancy} triangle measures fastest.
__global__ __launch_bounds__(1024) void k_pass1(const float* __restrict__ x,
                                                float* __restrict__ dsums,
                                                float* __restrict__ xbsums){
  __shared__ float rowdat[8][1024];   // [ks0..3, wz0..3][row-in-round]  32 KB
  __shared__ float txb[32][16];       // [i-local][py*4+pz]
  __shared__ float tbs[32][16];       // [i-local][jq*4+kq]
  int tid = threadIdx.x;
  int b = blockIdx.x;
  int mc   = b >> 1;
  int half = b & 1;
  const float* xp = x + (size_t)mc * NVOX;
  int chunk = tid & 15;
  int rbase = tid >> 4;        // j, 0..63
  float wq0,wq1,wq2,wq3; int lzc;
  {
    float cz = fminf(fmaxf((chunk*4+0.5f)*0.0625f-0.5f, 0.0f), 3.0f);
    lzc = (int)cz;  wq0 = cz - (float)lzc;
    cz = fminf(fmaxf((chunk*4+1.5f)*0.0625f-0.5f, 0.0f), 3.0f); wq1 = cz - (float)lzc;
    cz = fminf(fmaxf((chunk*4+2.5f)*0.0625f-0.5f, 0.0f), 3.0f); wq2 = cz - (float)lzc;
    cz = fminf(fmaxf((chunk*4+3.5f)*0.0625f-0.5f, 0.0f), 3.0f); wq3 = cz - (float)lzc;
  }
  int kb = chunk >> 2;
  for (int r2=0; r2<2; ++r2){
    int round = half*2 + r2;
#pragma unroll
    for (int itg=0; itg<4; ++itg){
      f4 u[4];
#pragma unroll
      for (int s=0;s<4;++s){
        int it = itg*4+s;
        int row = round*1024 + it*64 + rbase;
        u[s] = *reinterpret_cast<const f4*>(xp + (size_t)row * 64 + chunk*4);
      }
#pragma unroll
      for (int s=0;s<4;++s){
        int it = itg*4+s;
        int rir = it*64 + rbase;         // row-in-round
        f4 v = u[s];
        float ksP = (v.x+v.y)+(v.z+v.w);
        float wB = v.x*wq0 + v.y*wq1 + v.z*wq2 + v.w*wq3;
        float wA = ksP - wB;
        ksP += __shfl_xor(ksP, 1, 64);
        ksP += __shfl_xor(ksP, 2, 64);
        float w0 = (lzc==0)?wA:0.f;
        float w1 = (lzc==1)?wA:((lzc==0)?wB:0.f);
        float w2 = (lzc==2)?wA:((lzc==1)?wB:0.f);
        float w3 = (lzc==3)?wA:((lzc==2)?wB:0.f);
#pragma unroll
        for (int mk=1; mk<16; mk<<=1){
          w0 += __shfl_xor(w0, mk, 64);
          w1 += __shfl_xor(w1, mk, 64);
          w2 += __shfl_xor(w2, mk, 64);
          w3 += __shfl_xor(w3, mk, 64);
        }
        if ((chunk&3)==0) rowdat[kb][rir] = ksP;
        if (chunk==0) rowdat[4][rir]=w0;
        if (chunk==1) rowdat[5][rir]=w1;
        if (chunk==2) rowdat[6][rir]=w2;
        if (chunk==3) rowdat[7][rir]=w3;
      }
    }
    __syncthreads();
    if (tid < 256){            // xb j-collapse: thread = (i_loc, py, pz)
      int il = tid>>4, py=(tid>>2)&3, pz=tid&3;
      int base = il*64;
      float s=0.f;
      for (int jj=0; jj<64; ++jj){
        int j = (jj + tid) & 63;         // bank stagger
        float cj = fminf(fmaxf((j+0.5f)*0.0625f-0.5f, 0.0f), 3.0f);
        int lj=(int)cj; float wj=cj-(float)lj;
        float w = (py==lj)?(1.f-wj):((py==lj+1)?wj:0.f);
        s += w * rowdat[4+pz][base+j];
      }
      txb[r2*16+il][py*4+pz] = s;
    } else if (tid < 512){     // bs j-collapse: thread = (i_loc, jq, kq)
      int u2 = tid-256;
      int il = u2>>4, jq=(u2>>2)&3, kq=u2&3;
      int base = il*64 + jq*16;
      float s=0.f;
      for (int jj=0; jj<16; ++jj) s += rowdat[kq][base + ((jj+u2)&15)];
      tbs[r2*16+il][jq*4+kq] = s;
    }
    __syncthreads();
  }
  if (tid < 64){               // xb i-collapse over this half's 32 i-rows
    int px = tid>>4, py=(tid>>2)&3, pz=tid&3;
    float s=0.f;
    for (int il=0; il<32; ++il){
      int i = half*32 + il;
      float ci = fminf(fmaxf((i+0.5f)*0.0625f-0.5f, 0.0f), 3.0f);
      int li=(int)ci; float wi=ci-(float)li;
      float w = (px==li)?(1.f-wi):((px==li+1)?wi:0.f);
      s += w * txb[il][py*4+pz];
    }
    atomicAdd(&xbsums[(size_t)mc*64+tid], s);
  } else if (tid < 96){        // bs i-collapse: 32 cells (iq in this half)
    int p_loc = tid-64;                  // 0..31
    int iq_loc = p_loc>>4, inner = p_loc&15;
    float s=0.f;
    for (int il=iq_loc*16; il<iq_loc*16+16; ++il) s += tbs[il][inner];
    atomicAdd(&dsums[(size_t)mc*64 + (half*2+iq_loc)*16 + inner], s);
  }
}

// ---------------- pass 2: all tiny MLPs (single block) + wf->bf16 conversion ----------------
__global__ __launch_bounds__(256) void k_pass2(
    const float* __restrict__ dsums, const float* __restrict__ xbsums,
    const float* __restrict__ wq1, const float* __restrict__ bq1,
    const float* __restrict__ wq2, const float* __restrict__ bq2,
    const float* __restrict__ wa1, const float* __restrict__ ba1,
    const float* __restrict__ wa2, const float* __restrict__ ba2,
    const float* __restrict__ wf,  const float* __restrict__ bfv,
    const float* __restrict__ wg1, const float* __restrict__ bg1,
    const float* __restrict__ wg2, const float* __restrict__ bg2,
    float* __restrict__ wsa, float* __restrict__ wsgate,
    float* __restrict__ wsqw, float* __restrict__ wsinv,
    unsigned short* __restrict__ wfb,
    float* __restrict__ outp)
{
  __shared__ float sGap[256];
  __shared__ float sA[256];
  __shared__ float sCm[256];
  __shared__ float sG[256];
  __shared__ float sGG[16];
  __shared__ float sQw[4];
  int tid = threadIdx.x;
  int m = tid>>6, c = tid&63;
  for (int t = tid; t < 4096; t += 256) wfb[t] = f2b(wf[t]);
  {
    float s=0.f;
    const float* dp = dsums + (size_t)tid*64;
    for (int p=0;p<64;++p) s += dp[p];
    sGap[tid] = s * (1.0f/262144.0f);
  }
  {
    int p = c;
    float h0=0,h1=0,h2=0,h3=0;
    for (int cc=0; cc<64; ++cc){
      float dm = dsums[((size_t)(m*64+cc))*64+p] * (1.0f/4096.0f);
      h0 += dm * wa1[0*64+cc];
      h1 += dm * wa1[1*64+cc];
      h2 += dm * wa1[2*64+cc];
      h3 += dm * wa1[3*64+cc];
    }
    h0 = fmaxf(h0 + ba1[0], 0.f);
    h1 = fmaxf(h1 + ba1[1], 0.f);
    h2 = fmaxf(h2 + ba1[2], 0.f);
    h3 = fmaxf(h3 + ba1[3], 0.f);
    float s = h0*wa2[0] + h1*wa2[1] + h2*wa2[2] + h3*wa2[3] + ba2[0];
    float aa = sigm(s);
    sA[tid] = aa;
    wsa[tid] = aa;
  }
  __syncthreads();
  if (tid < 4){
    int mm = tid;
    float q0=0,q1=0,q2=0,q3=0;
    for (int cc=0; cc<64; ++cc){
      float g = sGap[mm*64+cc];
      q0 += g*wq1[0*64+cc];
      q1 += g*wq1[1*64+cc];
      q2 += g*wq1[2*64+cc];
      q3 += g*wq1[3*64+cc];
    }
    q0 = fmaxf(q0+bq1[0],0.f); q1 = fmaxf(q1+bq1[1],0.f);
    q2 = fmaxf(q2+bq1[2],0.f); q3 = fmaxf(q3+bq1[3],0.f);
    float s0 = sigm(q0*wq2[0]+q1*wq2[1]+q2*wq2[2]+q3*wq2[3]+bq2[0]);
    float s1 = sigm(q0*wq2[4]+q1*wq2[5]+q2*wq2[6]+q3*wq2[7]+bq2[1]);
    sQw[mm] = 0.5f*(s0+s1);
    outp[MB_TOT + mm]     = s0;  // boundary
    outp[MB_TOT + 4 + mm] = s1;  // semantic
  }
  __syncthreads();
  float qw_m = sQw[m];
  float T = sQw[0]+sQw[1]+sQw[2]+sQw[3];
  float inv_m = 1.0f/(T - qw_m);
  if (tid < 4){ wsqw[tid] = sQw[tid]; wsinv[tid] = 1.0f/(T - sQw[tid]); }
  {
    const float* xbp = xbsums + (size_t)tid*64;
    float s=0.f;
    for (int p=0;p<64;++p) s += sA[m*64+p]*xbp[p];
    sCm[tid] = qw_m * s * (1.0f/262144.0f);
  }
  __syncthreads();
  {
    int dd = c;
    float acc=0.f;
    for (int cc=0; cc<64; ++cc){
      float Sm = sCm[0*64+cc]+sCm[1*64+cc]+sCm[2*64+cc]+sCm[3*64+cc];
      float em = (Sm - sCm[m*64+cc]) * inv_m;
      acc += em * wf[dd*64+cc];
    }
    sG[tid] = acc + bfv[dd];
  }
  __syncthreads();
  if (tid < 16){
    int mm = tid>>2, k = tid&3;
    float acc=0.f;
    for (int dd=0; dd<64; ++dd) acc += sG[mm*64+dd]*wg1[k*64+dd];
    sGG[tid] = fmaxf(acc + bg1[k], 0.f);
  }
  __syncthreads();
  {
    float s = sGG[m*4+0]*wg2[c*4+0] + sGG[m*4+1]*wg2[c*4+1]
            + sGG[m*4+2]*wg2[c*4+2] + sGG[m*4+3]*wg2[c*4+3] + bg2[c];
    wsgate[tid] = sigm(s);
  }
}

// ---------------- pass 3: coalesced fp32 staging + MFMA + coalesced transposed store ----------
__global__ __launch_bounds__(256) void k_pass3(
    const float* __restrict__ x, const unsigned short* __restrict__ wfb,
    const float* __restrict__ bfv,
    const float* __restrict__ wsa, const float* __restrict__ wsgate,
    const float* __restrict__ wsqw, const float* __restrict__ wsinv,
    float* __restrict__ outp)
{
  __shared__ unsigned int xt[4][32][68];     // [m][cc-pair][vox] bf16 pairs; 16B-aligned rows
  __shared__ unsigned int fusedT[64][34];    // [dd][vox-pair] bf16 pairs
  __shared__ float aCell[4][64];
  __shared__ float gateL[4][64];
  __shared__ __align__(16) float auq[4][64];
  __shared__ float bfL[64];
  __shared__ float A2[4][4];
  int tid = threadIdx.x;
  int b = 4095 - (int)blockIdx.x;     // reversed tile order (L3 reuse from pass1)
  int i = b >> 6, j = b & 63;
  size_t V0 = (size_t)b * 64;
  int w    = tid >> 6;
  int lane = tid & 63;
  int ks   = lane >> 4;
  int r    = lane & 15;
  int vox16 = w << 4;

  const float* xw = x + (size_t)(w*64)*NVOX + V0 + r*4;
  f4 v[16];
#pragma unroll
  for (int rr=0; rr<16; ++rr){
    int cc = ks*16 + rr;
    v[rr] = *reinterpret_cast<const f4*>(xw + (size_t)cc*NVOX);
  }
  aCell[w][lane] = wsa[tid];
  gateL[w][lane] = wsgate[tid];
  if (tid < 64) bfL[tid] = bfv[tid];
#pragma unroll
  for (int rr=0; rr<16; rr+=2){
    u4v pk;
#pragma unroll
    for (int q=0;q<4;++q) pk[q] = cvtpk(v[rr][q], v[rr+1][q]);
    *reinterpret_cast<u4v*>(&xt[w][ks*8 + (rr>>1)][r*4]) = pk;
  }
  __syncthreads();

  if (tid < 16){
    int mm = tid>>2, pz = tid&3;
    float ci = fminf(fmaxf((i+0.5f)*0.0625f-0.5f,0.f),3.f);
    int li=(int)ci; float wi=ci-(float)li; int hiI=li<3?li+1:3;
    float cj = fminf(fmaxf((j+0.5f)*0.0625f-0.5f,0.f),3.f);
    int lj=(int)cj; float wj=cj-(float)lj; int hj=lj<3?lj+1:3;
    A2[mm][pz] = (1.f-wi)*((1.f-wj)*aCell[mm][li*16+lj*4+pz] + wj*aCell[mm][li*16+hj*4+pz])
               + wi*((1.f-wj)*aCell[mm][hiI*16+lj*4+pz] + wj*aCell[mm][hiI*16+hj*4+pz]);
  }
  __syncthreads();
  {
    int mm = tid>>6, z = tid&63;
    float cz = fminf(fmaxf((z+0.5f)*0.0625f-0.5f,0.f),3.f);
    int lz=(int)cz; float wzf=cz-(float)lz; int hz=lz<3?lz+1:3;
    auq[mm][z] = ((1.f-wzf)*A2[mm][lz] + wzf*A2[mm][hz]) * wsqw[mm];
  }
  __syncthreads();

  s8v bfr[4][2];
#pragma unroll
  for (int t=0;t<4;++t)
#pragma unroll
    for (int kk=0;kk<2;++kk)
      bfr[t][kk] = *reinterpret_cast<const s8v*>(&wfb[(t*16 + r)*64 + kk*32 + ks*8]);

  f4 acc[4][4];
#pragma unroll
  for (int mm=0;mm<4;++mm)
#pragma unroll
    for (int t=0;t<4;++t) acc[mm][t] = f4{0.f,0.f,0.f,0.f};

#pragma unroll
  for (int mm=0;mm<4;++mm){
    union { unsigned int u[4]; s8v s; } A0, A1;
#pragma unroll
    for (int q=0;q<4;++q){
      A0.u[q] = xt[mm][ks*4+q][vox16+r];
      A1.u[q] = xt[mm][16+ks*4+q][vox16+r];
    }
#pragma unroll
    for (int t=0;t<4;++t){
      acc[mm][t] = __builtin_amdgcn_mfma_f32_16x16x32_bf16(A0.s, bfr[t][0], acc[mm][t], 0,0,0);
      acc[mm][t] = __builtin_amdgcn_mfma_f32_16x16x32_bf16(A1.s, bfr[t][1], acc[mm][t], 0,0,0);
    }
  }

  f4 aq[4]; float invv[4];
#pragma unroll
  for (int mm=0;mm<4;++mm){
    aq[mm]  = *reinterpret_cast<const f4*>(&auq[mm][vox16 + 4*ks]);
    invv[mm] = wsinv[mm];
  }
  f4 FS[4];
#pragma unroll
  for (int t=0;t<4;++t){
    FS[t] = f4{0.f,0.f,0.f,0.f};
#pragma unroll
    for (int mm=0;mm<4;++mm)
#pragma unroll
      for (int q=0;q<4;++q) FS[t][q] += aq[mm][q]*acc[mm][t][q];
  }

  int g4 = tid >> 4;
  int r4l = tid & 15;
#pragma unroll
  for (int mm=0;mm<4;++mm){
#pragma unroll
    for (int t=0;t<4;++t){
      int dd = t*16 + r;
      float bfvv = bfL[dd];
      float f0 = (FS[t][0] - aq[mm][0]*acc[mm][t][0])*invv[mm] + bfvv;
      float f1 = (FS[t][1] - aq[mm][1]*acc[mm][t][1])*invv[mm] + bfvv;
      float f2 = (FS[t][2] - aq[mm][2]*acc[mm][t][2])*invv[mm] + bfvv;
      float f3 = (FS[t][3] - aq[mm][3]*acc[mm][t][3])*invv[mm] + bfvv;
      u2v pk2;
      pk2.x = cvtpk(f0, f1);
      pk2.y = cvtpk(f2, f3);
      *reinterpret_cast<u2v*>(&fusedT[dd][(vox16 + ks*4)>>1]) = pk2;
    }
    __syncthreads();
#pragma unroll
    for (int rr=0; rr<4; ++rr){
      int dd = rr*16 + g4;
      float g = gateL[mm][dd];
      u4v xu = *reinterpret_cast<const u4v*>(&xt[mm][dd>>1][r4l*4]);
      u2v fu = *reinterpret_cast<const u2v*>(&fusedT[dd][r4l*2]);
      f4 o;
      float x0 = (dd&1) ? bh(xu[0]) : bl(xu[0]);
      float x1 = (dd&1) ? bh(xu[1]) : bl(xu[1]);
      float x2 = (dd&1) ? bh(xu[2]) : bl(xu[2]);
      float x3 = (dd&1) ? bh(xu[3]) : bl(xu[3]);
      o[0] = x0 + g*bl(fu.x);
      o[1] = x1 + g*bh(fu.x);
      o[2] = x2 + g*bl(fu.y);
      o[3] = x3 + g*bh(fu.y);
      *reinterpret_cast<f4*>(outp + (size_t)(mm*64+dd)*NVOX + V0 + r4l*4) = o;
    }
    __syncthreads();
  }
}

extern "C" void kernel_launch(void* const* d_in, const int* in_sizes, int n_in,
                              void* d_out, int out_size, void* d_ws, size_t ws_size,
                              hipStream_t stream){
  const float* x   = (const float*)d_in[0];
  const float* wq1 = (const float*)d_in[1];
  const float* bq1 = (const float*)d_in[2];
  const float* wq2 = (const float*)d_in[3];
  const float* bq2 = (const float*)d_in[4];
  const float* wa1 = (const float*)d_in[5];
  const float* ba1 = (const float*)d_in[6];
  const float* wa2 = (const float*)d_in[7];
  const float* ba2 = (const float*)d_in[8];
  const float* wf  = (const float*)d_in[9];
  const float* bfv = (const float*)d_in[10];
  const float* wg1 = (const float*)d_in[11];
  const float* bg1 = (const float*)d_in[12];
  const float* wg2 = (const float*)d_in[13];
  const float* bg2 = (const float*)d_in[14];
  float* outp = (float*)d_out;
  float* w = (float*)d_ws;
  float* dsums  = w;            // 16384 floats
  float* xbsums = w + 16384;    // 16384 floats
  float* wsa    = w + 32768;    // 256
  float* wsgate = w + 33024;    // 256
  float* wsqw   = w + 33280;    // 4
  float* wsinv  = w + 33284;    // 4
  unsigned short* wfb = (unsigned short*)(w + 33288);  // 4096 bf16
  hipMemsetAsync(w, 0, 32768*sizeof(float), stream);
  hipLaunchKernelGGL(k_pass1, dim3(512), dim3(1024), 0, stream, x, dsums, xbsums);
  hipLaunchKernelGGL(k_pass2, dim3(1), dim3(256), 0, stream, dsums, xbsums,
                     wq1,bq1,wq2,bq2,wa1,ba1,wa2,ba2,wf,bfv,wg1,bg1,wg2,bg2,
                     wsa, wsgate, wsqw, wsinv, wfb, outp);
  hipLaunchKernelGGL(k_pass3, dim3(4096), dim3(256), 0, stream, x, wfb, bfv,
                     wsa, wsgate, wsqw, wsinv, outp);
}